// Round 1
// baseline (1598.679 us; speedup 1.0000x reference)
//
#include <hip/hip_runtime.h>
#include <hip/hip_bf16.h>
#include <math.h>

// Problem constants (B=1)
#define HH 16
#define WW 16
#define DD 16
#define LL 4096          // H*W*Dd
#define CC 48            // d_model
#define DIN 48           // d_inner
#define NN 16            // d_state
#define RR 3             // dt_rank
#define KK 8             // scan directions
#define KD 384           // K*DIN

// ---------------- Kernel 1: in_proj  xz[l,e] = sum_c x[l,c]*W[e,c] ----------
// xm stored channels-first (DIN, L); z stored (L, DIN)
__global__ __launch_bounds__(256) void k_inproj(const float* __restrict__ x,
                                                const float* __restrict__ W,
                                                float* __restrict__ xm,
                                                float* __restrict__ z) {
    int tid = blockIdx.x * 256 + threadIdx.x;          // l*96 + e
    if (tid >= LL * 96) return;
    int e = tid % 96, l = tid / 96;
    const float* xr = x + l * CC;
    const float* wr = W + e * CC;
    float acc = 0.f;
#pragma unroll
    for (int c = 0; c < CC; ++c) acc += xr[c] * wr[c];
    if (e < DIN) xm[e * LL + l] = acc;
    else         z[l * DIN + (e - DIN)] = acc;
}

// ------------- Kernel 2: depthwise 3x3x3 conv + bias + SiLU -----------------
__global__ __launch_bounds__(256) void k_conv(const float* __restrict__ xm,
                                              const float* __restrict__ cw,
                                              const float* __restrict__ cb,
                                              float* __restrict__ xc) {
    int tid = blockIdx.x * 256 + threadIdx.x;          // d*LL + s
    if (tid >= DIN * LL) return;
    int s = tid & (LL - 1), d = tid >> 12;
    int dd = s & 15, w = (s >> 4) & 15, h = s >> 8;
    const float* wp = cw + d * 27;
    const float* xp = xm + d * LL;
    float acc = 0.f;
#pragma unroll
    for (int i = -1; i <= 1; ++i) {
        int hh = h + i; if (hh < 0 || hh > 15) continue;
#pragma unroll
        for (int j = -1; j <= 1; ++j) {
            int ww2 = w + j; if (ww2 < 0 || ww2 > 15) continue;
#pragma unroll
            for (int q = -1; q <= 1; ++q) {
                int dd2 = dd + q; if (dd2 < 0 || dd2 > 15) continue;
                acc += wp[(i + 1) * 9 + (j + 1) * 3 + (q + 1)]
                     * xp[hh * 256 + ww2 * 16 + dd2];
            }
        }
    }
    acc += cb[d];
    xc[tid] = acc / (1.f + __expf(-acc));              // SiLU
}

// ------------- Kernel 3: build 8 directional orderings xs (K,DIN,L) ---------
__global__ __launch_bounds__(256) void k_scatter(const float* __restrict__ xc,
                                                 float* __restrict__ xs) {
    int tid = blockIdx.x * 256 + threadIdx.x;          // (k*48+d)*LL + l
    if (tid >= KD * LL) return;
    int l = tid & (LL - 1);
    int gd = tid >> 12;                                // k*48+d
    int d = gd % DIN, k = gd / DIN;
    int ll = (k & 4) ? (LL - 1 - l) : l;
    int a = ll >> 8, b = (ll >> 4) & 15, c = ll & 15;
    int src;
    switch (k & 3) {
        case 0: src = ll;                     break;   // (h,w,dd)
        case 1: src = b * 256 + a * 16 + c;   break;   // (w,h,dd)
        case 2: src = c * 256 + b * 16 + a;   break;   // (dd,w,h)
        default: src = a * 256 + c * 16 + b;  break;   // (h,dd,w)
    }
    xs[tid] = xc[d * LL + src];
}

// ------------- Kernel 4: x_dbl[k,l,c] = sum_d xs[k,d,l]*xpw[k,c,d] ----------
__global__ __launch_bounds__(256) void k_xproj(const float* __restrict__ xs,
                                               const float* __restrict__ xpw,
                                               float* __restrict__ xdbl) {
    int tid = blockIdx.x * 256 + threadIdx.x;          // (k*LL + l)*35 + c
    if (tid >= KK * LL * 35) return;
    int c = tid % 35;
    int kl = tid / 35;
    int l = kl & (LL - 1), k = kl >> 12;
    const float* wr = xpw + (k * 35 + c) * DIN;
    const float* xr = xs + (k * DIN) * LL + l;         // stride LL per d
    float acc = 0.f;
#pragma unroll
    for (int d = 0; d < DIN; ++d) acc += xr[d * LL] * wr[d];
    xdbl[tid] = acc;
}

// ------------- Kernel 5: delta = softplus(dts@dtw + bias), (K,DIN,L) --------
__global__ __launch_bounds__(256) void k_delta(const float* __restrict__ xdbl,
                                               const float* __restrict__ dtw,
                                               const float* __restrict__ dtb,
                                               float* __restrict__ dsp) {
    int tid = blockIdx.x * 256 + threadIdx.x;          // (k*48+d)*LL + l
    if (tid >= KD * LL) return;
    int l = tid & (LL - 1);
    int gd = tid >> 12;                                // k*48+d
    int k = gd / DIN;
    const float* xr = xdbl + (k * LL + l) * 35;
    const float* wr = dtw + gd * RR;
    float v = xr[0] * wr[0] + xr[1] * wr[1] + xr[2] * wr[2] + dtb[gd];
    dsp[tid] = (v > 20.f) ? v : log1pf(__expf(v));     // stable softplus
}

// ------------- Kernel 6: selective scan -------------------------------------
// 16 lanes per (k,d) group; lane = state index n. Sequential over L.
__global__ __launch_bounds__(256) void k_scan(const float* __restrict__ xs,
                                              const float* __restrict__ dsp,
                                              const float* __restrict__ xdbl,
                                              const float* __restrict__ A_logs,
                                              const float* __restrict__ Ds,
                                              float* __restrict__ y) {
    int t = blockIdx.x * 256 + threadIdx.x;
    int gid = t >> 4;                                  // k*48+d, 0..383
    int n = t & 15;
    if (gid >= KD) return;
    int k = gid / DIN;
    float A = -__expf(A_logs[gid * NN + n]);
    float Dv = Ds[gid];
    const float* up = xs + gid * LL;
    const float* dp = dsp + gid * LL;
    const float* bp = xdbl + (size_t)(k * LL) * 35 + 3 + n;
    const float* cp = xdbl + (size_t)(k * LL) * 35 + 19 + n;
    float* yp = y + gid * LL;
    float h = 0.f;
#pragma unroll 4
    for (int l = 0; l < LL; ++l) {
        float delta = dp[l];
        float u = up[l];
        float Bv = bp[(size_t)l * 35];
        float Cv = cp[(size_t)l * 35];
        float dA = __expf(delta * A);
        h = h * dA + delta * u * Bv;
        float p = h * Cv;
        p += __shfl_xor(p, 1, 64);
        p += __shfl_xor(p, 2, 64);
        p += __shfl_xor(p, 4, 64);
        p += __shfl_xor(p, 8, 64);
        if (n == 0) yp[l] = p + Dv * u;
    }
}

// ------------- Kernel 7: merge dirs + LayerNorm + gate + out_proj -----------
__global__ __launch_bounds__(64) void k_final(const float* __restrict__ y,
                                              const float* __restrict__ z,
                                              const float* __restrict__ nw,
                                              const float* __restrict__ nb,
                                              const float* __restrict__ opw,
                                              float* __restrict__ out) {
    int s = blockIdx.x;                                // spatial (h,w,dd)
    int lane = threadIdx.x;                            // 0..63
    int dd = s & 15, w = (s >> 4) & 15, h = s >> 8;
    int l0 = s;
    int l1 = w * 256 + h * 16 + dd;
    int l2 = dd * 256 + w * 16 + h;
    int l3 = h * 256 + dd * 16 + w;
    __shared__ float g[DIN];
    float val = 0.f;
    if (lane < DIN) {
        int d = lane;
        val = y[(0 * DIN + d) * LL + l0] + y[(4 * DIN + d) * LL + (LL - 1 - l0)]
            + y[(1 * DIN + d) * LL + l1] + y[(5 * DIN + d) * LL + (LL - 1 - l1)]
            + y[(2 * DIN + d) * LL + l2] + y[(6 * DIN + d) * LL + (LL - 1 - l2)]
            + y[(3 * DIN + d) * LL + l3] + y[(7 * DIN + d) * LL + (LL - 1 - l3)];
    }
    // mean over 48 channels (lanes >=48 contribute 0)
    float m = val;
#pragma unroll
    for (int o = 32; o >= 1; o >>= 1) m += __shfl_xor(m, o, 64);
    m *= (1.f / 48.f);
    float dv = (lane < DIN) ? (val - m) : 0.f;
    float v2 = dv * dv;
#pragma unroll
    for (int o = 32; o >= 1; o >>= 1) v2 += __shfl_xor(v2, o, 64);
    v2 *= (1.f / 48.f);
    float inv = rsqrtf(v2 + 1e-5f);
    if (lane < DIN) {
        float yn = dv * inv * nw[lane] + nb[lane];
        float zz = z[s * DIN + lane];
        g[lane] = yn * (zz / (1.f + __expf(-zz)));     // * silu(z)
    }
    __syncthreads();
    if (lane < DIN) {
        const float* wr = opw + lane * DIN;            // out_proj_w[c, e], c=lane
        float acc = 0.f;
#pragma unroll
        for (int e = 0; e < DIN; ++e) acc += g[e] * wr[e];
        out[s * CC + lane] = acc;
    }
}

extern "C" void kernel_launch(void* const* d_in, const int* in_sizes, int n_in,
                              void* d_out, int out_size, void* d_ws, size_t ws_size,
                              hipStream_t stream) {
    const float* x      = (const float*)d_in[0];
    const float* ipw    = (const float*)d_in[1];
    const float* cw     = (const float*)d_in[2];
    const float* cb     = (const float*)d_in[3];
    const float* xpw    = (const float*)d_in[4];
    const float* dtw    = (const float*)d_in[5];
    const float* dtb    = (const float*)d_in[6];
    const float* A_logs = (const float*)d_in[7];
    const float* Ds     = (const float*)d_in[8];
    const float* nw     = (const float*)d_in[9];
    const float* nb     = (const float*)d_in[10];
    const float* opw    = (const float*)d_in[11];
    float* out = (float*)d_out;

    float* ws   = (float*)d_ws;
    float* xm   = ws;                      // DIN*LL        = 196608
    float* z    = xm + DIN * LL;           // LL*DIN        = 196608
    float* xc   = z + LL * DIN;            // DIN*LL        = 196608
    float* xs   = xc + DIN * LL;           // KD*LL         = 1572864
    float* xdbl = xs + (size_t)KD * LL;    // K*LL*35       = 1146880
    float* dsp  = xdbl + (size_t)KK * LL * 35;  // KD*LL    = 1572864
    float* y    = dsp + (size_t)KD * LL;   // KD*LL         = 1572864

    k_inproj<<<(LL * 96 + 255) / 256, 256, 0, stream>>>(x, ipw, xm, z);
    k_conv<<<(DIN * LL + 255) / 256, 256, 0, stream>>>(xm, cw, cb, xc);
    k_scatter<<<(KD * LL + 255) / 256, 256, 0, stream>>>(xc, xs);
    k_xproj<<<(KK * LL * 35 + 255) / 256, 256, 0, stream>>>(xs, xpw, xdbl);
    k_delta<<<(KD * LL + 255) / 256, 256, 0, stream>>>(xdbl, dtw, dtb, dsp);
    k_scan<<<(KD * NN + 255) / 256, 256, 0, stream>>>(xs, dsp, xdbl, A_logs, Ds, y);
    k_final<<<LL, 64, 0, stream>>>(y, z, nw, nb, opw, out);
}

// Round 2
// 194.117 us; speedup vs baseline: 8.2357x; 8.2357x over previous
//
#include <hip/hip_runtime.h>
#include <hip/hip_bf16.h>
#include <math.h>

// Problem constants (B=1)
#define HH 16
#define WW 16
#define DD 16
#define LL 4096          // H*W*Dd
#define CC 48            // d_model
#define DIN 48           // d_inner
#define NN 16            // d_state
#define RR 3             // dt_rank
#define KK 8             // scan directions
#define KD 384           // K*DIN
#define NCH 64           // chunks along L
#define CHL 64           // chunk length (NCH*CHL == LL)

// ---------------- Kernel 1: in_proj  xz[l,e] = sum_c x[l,c]*W[e,c] ----------
__global__ __launch_bounds__(256) void k_inproj(const float* __restrict__ x,
                                                const float* __restrict__ W,
                                                float* __restrict__ xm,
                                                float* __restrict__ z) {
    int tid = blockIdx.x * 256 + threadIdx.x;          // l*96 + e
    if (tid >= LL * 96) return;
    int e = tid % 96, l = tid / 96;
    const float* xr = x + l * CC;
    const float* wr = W + e * CC;
    float acc = 0.f;
#pragma unroll
    for (int c = 0; c < CC; ++c) acc += xr[c] * wr[c];
    if (e < DIN) xm[e * LL + l] = acc;
    else         z[l * DIN + (e - DIN)] = acc;
}

// ------------- Kernel 2: depthwise 3x3x3 conv + bias + SiLU -----------------
__global__ __launch_bounds__(256) void k_conv(const float* __restrict__ xm,
                                              const float* __restrict__ cw,
                                              const float* __restrict__ cb,
                                              float* __restrict__ xc) {
    int tid = blockIdx.x * 256 + threadIdx.x;          // d*LL + s
    if (tid >= DIN * LL) return;
    int s = tid & (LL - 1), d = tid >> 12;
    int dd = s & 15, w = (s >> 4) & 15, h = s >> 8;
    const float* wp = cw + d * 27;
    const float* xp = xm + d * LL;
    float acc = 0.f;
#pragma unroll
    for (int i = -1; i <= 1; ++i) {
        int hh = h + i; if (hh < 0 || hh > 15) continue;
#pragma unroll
        for (int j = -1; j <= 1; ++j) {
            int ww2 = w + j; if (ww2 < 0 || ww2 > 15) continue;
#pragma unroll
            for (int q = -1; q <= 1; ++q) {
                int dd2 = dd + q; if (dd2 < 0 || dd2 > 15) continue;
                acc += wp[(i + 1) * 9 + (j + 1) * 3 + (q + 1)]
                     * xp[hh * 256 + ww2 * 16 + dd2];
            }
        }
    }
    acc += cb[d];
    xc[tid] = acc / (1.f + __expf(-acc));              // SiLU
}

// ------------- Kernel 3: build 8 directional orderings xs (K,DIN,L) ---------
__global__ __launch_bounds__(256) void k_scatter(const float* __restrict__ xc,
                                                 float* __restrict__ xs) {
    int tid = blockIdx.x * 256 + threadIdx.x;          // (k*48+d)*LL + l
    if (tid >= KD * LL) return;
    int l = tid & (LL - 1);
    int gd = tid >> 12;                                // k*48+d
    int d = gd % DIN, k = gd / DIN;
    int ll = (k & 4) ? (LL - 1 - l) : l;
    int a = ll >> 8, b = (ll >> 4) & 15, c = ll & 15;
    int src;
    switch (k & 3) {
        case 0: src = ll;                     break;   // (h,w,dd)
        case 1: src = b * 256 + a * 16 + c;   break;   // (w,h,dd)
        case 2: src = c * 256 + b * 16 + a;   break;   // (dd,w,h)
        default: src = a * 256 + c * 16 + b;  break;   // (h,dd,w)
    }
    xs[tid] = xc[d * LL + src];
}

// ------------- Kernel 4: x_dbl[k,l,c] = sum_d xs[k,d,l]*xpw[k,c,d] ----------
__global__ __launch_bounds__(256) void k_xproj(const float* __restrict__ xs,
                                               const float* __restrict__ xpw,
                                               float* __restrict__ xdbl) {
    int tid = blockIdx.x * 256 + threadIdx.x;          // (k*LL + l)*35 + c
    if (tid >= KK * LL * 35) return;
    int c = tid % 35;
    int kl = tid / 35;
    int l = kl & (LL - 1), k = kl >> 12;
    const float* wr = xpw + (k * 35 + c) * DIN;
    const float* xr = xs + (k * DIN) * LL + l;         // stride LL per d
    float acc = 0.f;
#pragma unroll
    for (int d = 0; d < DIN; ++d) acc += xr[d * LL] * wr[d];
    xdbl[tid] = acc;
}

// ------------- Kernel 5: delta = softplus(dts@dtw + bias), (K,DIN,L) --------
__global__ __launch_bounds__(256) void k_delta(const float* __restrict__ xdbl,
                                               const float* __restrict__ dtw,
                                               const float* __restrict__ dtb,
                                               float* __restrict__ dsp) {
    int tid = blockIdx.x * 256 + threadIdx.x;          // (k*48+d)*LL + l
    if (tid >= KD * LL) return;
    int l = tid & (LL - 1);
    int gd = tid >> 12;                                // k*48+d
    int k = gd / DIN;
    const float* xr = xdbl + (k * LL + l) * 35;
    const float* wr = dtw + gd * RR;
    float v = xr[0] * wr[0] + xr[1] * wr[1] + xr[2] * wr[2] + dtb[gd];
    dsp[tid] = (v > 20.f) ? v : log1pf(__expf(v));     // stable softplus
}

// ------------- Selective scan: 3-phase chunked parallel scan ----------------
// Thread mapping (phases 1/3): t = (gid*NCH + c)*16 + n
//   n = state index (lanes 0..15 within quad), c = chunk, gid = k*DIN+d
// Phase 1: local scan per chunk (h starts at 0), emit prodA + hfin summaries.
__global__ __launch_bounds__(256) void k_scan1(const float* __restrict__ xs,
                                               const float* __restrict__ dsp,
                                               const float* __restrict__ xdbl,
                                               const float* __restrict__ A_logs,
                                               float* __restrict__ prodA,
                                               float* __restrict__ hfin) {
    int t = blockIdx.x * 256 + threadIdx.x;
    if (t >= KD * NCH * NN) return;
    int n = t & 15;
    int gc = t >> 4;                                   // gid*NCH + c
    int c = gc & (NCH - 1);
    int gid = gc >> 6;                                 // /NCH
    int k = gid / DIN;
    float A = -__expf(A_logs[gid * NN + n]);
    const float* dp = dsp + gid * LL + c * CHL;
    const float* up = xs + gid * LL + c * CHL;
    const float* bp = xdbl + ((size_t)(k * LL + c * CHL)) * 35 + 3 + n;
    float h = 0.f, pa = 1.f;
#pragma unroll 4
    for (int i = 0; i < CHL; ++i) {
        float delta = dp[i];
        float u = up[i];
        float Bv = bp[(size_t)i * 35];
        float dA = __expf(delta * A);
        h = h * dA + delta * u * Bv;
        pa *= dA;
    }
    prodA[t] = pa;
    hfin[t] = h;
}

// Phase 2: sequential combine across the 64 chunk summaries (tiny).
// h0[c] = incoming state for chunk c.
__global__ __launch_bounds__(256) void k_scan2(const float* __restrict__ prodA,
                                               const float* __restrict__ hfin,
                                               float* __restrict__ h0) {
    int t = blockIdx.x * 256 + threadIdx.x;            // gid*16 + n
    if (t >= KD * NN) return;
    int n = t & 15;
    int gid = t >> 4;
    size_t base = (size_t)gid * NCH * 16 + n;
    float h = 0.f;
#pragma unroll 4
    for (int c = 0; c < NCH; ++c) {
        size_t idx = base + (size_t)c * 16;
        h0[idx] = h;
        h = h * prodA[idx] + hfin[idx];
    }
}

// Phase 3: re-scan each chunk seeded with h0, emit y.
__global__ __launch_bounds__(256) void k_scan3(const float* __restrict__ xs,
                                               const float* __restrict__ dsp,
                                               const float* __restrict__ xdbl,
                                               const float* __restrict__ A_logs,
                                               const float* __restrict__ Ds,
                                               const float* __restrict__ h0,
                                               float* __restrict__ y) {
    int t = blockIdx.x * 256 + threadIdx.x;
    if (t >= KD * NCH * NN) return;
    int n = t & 15;
    int gc = t >> 4;
    int c = gc & (NCH - 1);
    int gid = gc >> 6;
    int k = gid / DIN;
    float A = -__expf(A_logs[gid * NN + n]);
    float Dv = Ds[gid];
    const float* dp = dsp + gid * LL + c * CHL;
    const float* up = xs + gid * LL + c * CHL;
    const float* bp = xdbl + ((size_t)(k * LL + c * CHL)) * 35 + 3 + n;
    const float* cp = xdbl + ((size_t)(k * LL + c * CHL)) * 35 + 19 + n;
    float* yp = y + gid * LL + c * CHL;
    float h = h0[t];
#pragma unroll 4
    for (int i = 0; i < CHL; ++i) {
        float delta = dp[i];
        float u = up[i];
        float Bv = bp[(size_t)i * 35];
        float Cv = cp[(size_t)i * 35];
        float dA = __expf(delta * A);
        h = h * dA + delta * u * Bv;
        float p = h * Cv;
        p += __shfl_xor(p, 1, 64);
        p += __shfl_xor(p, 2, 64);
        p += __shfl_xor(p, 4, 64);
        p += __shfl_xor(p, 8, 64);
        if (n == 0) yp[i] = p + Dv * u;
    }
}

// ------------- Kernel 7: merge dirs + LayerNorm + gate + out_proj -----------
__global__ __launch_bounds__(64) void k_final(const float* __restrict__ y,
                                              const float* __restrict__ z,
                                              const float* __restrict__ nw,
                                              const float* __restrict__ nb,
                                              const float* __restrict__ opw,
                                              float* __restrict__ out) {
    int s = blockIdx.x;                                // spatial (h,w,dd)
    int lane = threadIdx.x;                            // 0..63
    int dd = s & 15, w = (s >> 4) & 15, h = s >> 8;
    int l0 = s;
    int l1 = w * 256 + h * 16 + dd;
    int l2 = dd * 256 + w * 16 + h;
    int l3 = h * 256 + dd * 16 + w;
    __shared__ float g[DIN];
    float val = 0.f;
    if (lane < DIN) {
        int d = lane;
        val = y[(0 * DIN + d) * LL + l0] + y[(4 * DIN + d) * LL + (LL - 1 - l0)]
            + y[(1 * DIN + d) * LL + l1] + y[(5 * DIN + d) * LL + (LL - 1 - l1)]
            + y[(2 * DIN + d) * LL + l2] + y[(6 * DIN + d) * LL + (LL - 1 - l2)]
            + y[(3 * DIN + d) * LL + l3] + y[(7 * DIN + d) * LL + (LL - 1 - l3)];
    }
    float m = val;
#pragma unroll
    for (int o = 32; o >= 1; o >>= 1) m += __shfl_xor(m, o, 64);
    m *= (1.f / 48.f);
    float dv = (lane < DIN) ? (val - m) : 0.f;
    float v2 = dv * dv;
#pragma unroll
    for (int o = 32; o >= 1; o >>= 1) v2 += __shfl_xor(v2, o, 64);
    v2 *= (1.f / 48.f);
    float inv = rsqrtf(v2 + 1e-5f);
    if (lane < DIN) {
        float yn = dv * inv * nw[lane] + nb[lane];
        float zz = z[s * DIN + lane];
        g[lane] = yn * (zz / (1.f + __expf(-zz)));     // * silu(z)
    }
    __syncthreads();
    if (lane < DIN) {
        const float* wr = opw + lane * DIN;            // out_proj_w[c, e], c=lane
        float acc = 0.f;
#pragma unroll
        for (int e = 0; e < DIN; ++e) acc += g[e] * wr[e];
        out[s * CC + lane] = acc;
    }
}

extern "C" void kernel_launch(void* const* d_in, const int* in_sizes, int n_in,
                              void* d_out, int out_size, void* d_ws, size_t ws_size,
                              hipStream_t stream) {
    const float* x      = (const float*)d_in[0];
    const float* ipw    = (const float*)d_in[1];
    const float* cw     = (const float*)d_in[2];
    const float* cb     = (const float*)d_in[3];
    const float* xpw    = (const float*)d_in[4];
    const float* dtw    = (const float*)d_in[5];
    const float* dtb    = (const float*)d_in[6];
    const float* A_logs = (const float*)d_in[7];
    const float* Ds     = (const float*)d_in[8];
    const float* nw     = (const float*)d_in[9];
    const float* nb     = (const float*)d_in[10];
    const float* opw    = (const float*)d_in[11];
    float* out = (float*)d_out;

    float* ws    = (float*)d_ws;
    float* xm    = ws;                         // DIN*LL
    float* z     = xm + DIN * LL;              // LL*DIN
    float* xc    = z + LL * DIN;               // DIN*LL
    float* xs    = xc + DIN * LL;              // KD*LL
    float* xdbl  = xs + (size_t)KD * LL;       // K*LL*35
    float* dsp   = xdbl + (size_t)KK * LL * 35; // KD*LL
    float* y     = dsp + (size_t)KD * LL;      // KD*LL
    float* prodA = y + (size_t)KD * LL;        // KD*NCH*16 = 393216
    float* hfin  = prodA + (size_t)KD * NCH * 16;
    float* h0    = hfin + (size_t)KD * NCH * 16;

    k_inproj<<<(LL * 96 + 255) / 256, 256, 0, stream>>>(x, ipw, xm, z);
    k_conv<<<(DIN * LL + 255) / 256, 256, 0, stream>>>(xm, cw, cb, xc);
    k_scatter<<<(KD * LL + 255) / 256, 256, 0, stream>>>(xc, xs);
    k_xproj<<<(KK * LL * 35 + 255) / 256, 256, 0, stream>>>(xs, xpw, xdbl);
    k_delta<<<(KD * LL + 255) / 256, 256, 0, stream>>>(xdbl, dtw, dtb, dsp);

    int scan_threads = KD * NCH * NN;                  // 393216
    k_scan1<<<(scan_threads + 255) / 256, 256, 0, stream>>>(xs, dsp, xdbl, A_logs, prodA, hfin);
    k_scan2<<<(KD * NN + 255) / 256, 256, 0, stream>>>(prodA, hfin, h0);
    k_scan3<<<(scan_threads + 255) / 256, 256, 0, stream>>>(xs, dsp, xdbl, A_logs, Ds, h0, y);

    k_final<<<LL, 64, 0, stream>>>(y, z, nw, nb, opw, out);
}

// Round 3
// 176.674 us; speedup vs baseline: 9.0487x; 1.0987x over previous
//
#include <hip/hip_runtime.h>
#include <hip/hip_bf16.h>
#include <math.h>

// Problem constants (B=1)
#define HH 16
#define WW 16
#define DD 16
#define LL 4096          // H*W*Dd
#define CC 48            // d_model
#define DIN 48           // d_inner
#define NN 16            // d_state
#define RR 3             // dt_rank
#define KK 8             // scan directions
#define KD 384           // K*DIN
#define NCH 128          // chunks along L
#define CHL 32           // chunk length (NCH*CHL == LL)

// ---------------- Kernel 1: in_proj  xz[l,e] = sum_c x[l,c]*W[e,c] ----------
__global__ __launch_bounds__(256) void k_inproj(const float* __restrict__ x,
                                                const float* __restrict__ W,
                                                float* __restrict__ xm,
                                                float* __restrict__ z) {
    int tid = blockIdx.x * 256 + threadIdx.x;          // l*96 + e
    if (tid >= LL * 96) return;
    int e = tid % 96, l = tid / 96;
    const float4* xr = (const float4*)(x + l * CC);
    const float4* wr = (const float4*)(W + e * CC);
    float acc = 0.f;
#pragma unroll
    for (int c4 = 0; c4 < CC / 4; ++c4) {
        float4 a = xr[c4], b = wr[c4];
        acc += a.x * b.x + a.y * b.y + a.z * b.z + a.w * b.w;
    }
    if (e < DIN) xm[e * LL + l] = acc;
    else         z[l * DIN + (e - DIN)] = acc;
}

// ------------- Kernel 2: depthwise 3x3x3 conv + bias + SiLU -----------------
__global__ __launch_bounds__(256) void k_conv(const float* __restrict__ xm,
                                              const float* __restrict__ cw,
                                              const float* __restrict__ cb,
                                              float* __restrict__ xc) {
    int tid = blockIdx.x * 256 + threadIdx.x;          // d*LL + s
    if (tid >= DIN * LL) return;
    int s = tid & (LL - 1), d = tid >> 12;
    int dd = s & 15, w = (s >> 4) & 15, h = s >> 8;
    const float* wp = cw + d * 27;
    const float* xp = xm + d * LL;
    float acc = 0.f;
#pragma unroll
    for (int i = -1; i <= 1; ++i) {
        int hh = h + i; if (hh < 0 || hh > 15) continue;
#pragma unroll
        for (int j = -1; j <= 1; ++j) {
            int ww2 = w + j; if (ww2 < 0 || ww2 > 15) continue;
#pragma unroll
            for (int q = -1; q <= 1; ++q) {
                int dd2 = dd + q; if (dd2 < 0 || dd2 > 15) continue;
                acc += wp[(i + 1) * 9 + (j + 1) * 3 + (q + 1)]
                     * xp[hh * 256 + ww2 * 16 + dd2];
            }
        }
    }
    acc += cb[d];
    xc[tid] = acc / (1.f + __expf(-acc));              // SiLU
}

// ------------- Kernel 3: build 8 directional orderings xs (K,DIN,L) ---------
// one thread per (gd, l-quad): 4 gathered reads, one float4 write
__global__ __launch_bounds__(256) void k_scatter(const float* __restrict__ xc,
                                                 float* __restrict__ xs) {
    int tid = blockIdx.x * 256 + threadIdx.x;          // gd*(LL/4) + l4
    if (tid >= KD * (LL / 4)) return;
    int l4 = tid & (LL / 4 - 1);
    int gd = tid >> 10;                                // k*48+d
    int d = gd % DIN, k = gd / DIN;
    const float* xp = xc + d * LL;
    float4 v;
#pragma unroll
    for (int j = 0; j < 4; ++j) {
        int l = l4 * 4 + j;
        int ll = (k & 4) ? (LL - 1 - l) : l;
        int a = ll >> 8, b = (ll >> 4) & 15, c = ll & 15;
        int src;
        switch (k & 3) {
            case 0: src = ll;                     break;   // (h,w,dd)
            case 1: src = b * 256 + a * 16 + c;   break;   // (w,h,dd)
            case 2: src = c * 256 + b * 16 + a;   break;   // (dd,w,h)
            default: src = a * 256 + c * 16 + b;  break;   // (h,dd,w)
        }
        (&v.x)[j] = xp[src];
    }
    ((float4*)xs)[tid] = v;
}

// ------------- Kernel 4: x_dbl[k,l,c] = sum_d xs[k,d,l]*xpw[k,c,d] ----------
// one thread per (k, c, l-quad): float4 loads along l, 4 outputs
__global__ __launch_bounds__(256) void k_xproj(const float* __restrict__ xs,
                                               const float* __restrict__ xpw,
                                               float* __restrict__ xdbl) {
    int tid = blockIdx.x * 256 + threadIdx.x;          // (k*(LL/4)+l4)*35 + c
    if (tid >= KK * (LL / 4) * 35) return;
    int c = tid % 35;
    int kl = tid / 35;
    int l4 = kl & (LL / 4 - 1), k = kl >> 10;
    const float* wr = xpw + (k * 35 + c) * DIN;
    const float4* xr = (const float4*)(xs + (size_t)(k * DIN) * LL + l4 * 4);
    float4 acc = {0.f, 0.f, 0.f, 0.f};
#pragma unroll
    for (int d = 0; d < DIN; ++d) {
        float4 v = xr[(size_t)d * (LL / 4)];
        float w = wr[d];
        acc.x += v.x * w; acc.y += v.y * w; acc.z += v.z * w; acc.w += v.w * w;
    }
    float* o = xdbl + ((size_t)(k * LL + l4 * 4)) * 35 + c;
    o[0] = acc.x; o[35] = acc.y; o[70] = acc.z; o[105] = acc.w;
}

// ------------- Kernel 5: delta = softplus(dts@dtw + bias), (K,DIN,L) --------
__global__ __launch_bounds__(256) void k_delta(const float* __restrict__ xdbl,
                                               const float* __restrict__ dtw,
                                               const float* __restrict__ dtb,
                                               float* __restrict__ dsp) {
    int tid = blockIdx.x * 256 + threadIdx.x;          // gd*(LL/4) + l4
    if (tid >= KD * (LL / 4)) return;
    int l4 = tid & (LL / 4 - 1);
    int gd = tid >> 10;                                // k*48+d
    int k = gd / DIN;
    const float* wr = dtw + gd * RR;
    float w0 = wr[0], w1 = wr[1], w2 = wr[2], bb = dtb[gd];
    const float* xr = xdbl + ((size_t)(k * LL + l4 * 4)) * 35;
    float4 o;
#pragma unroll
    for (int j = 0; j < 4; ++j) {
        const float* xj = xr + j * 35;
        float v = xj[0] * w0 + xj[1] * w1 + xj[2] * w2 + bb;
        (&o.x)[j] = (v > 20.f) ? v : log1pf(__expf(v));
    }
    ((float4*)dsp)[tid] = o;
}

// ------------- Selective scan: 3-phase chunked parallel scan ----------------
// Thread mapping (phases 1/3): t = (gid*NCH + c)*16 + n
// Phase 1: local scan per chunk (h starts at 0), emit prodA + hfin summaries.
__global__ __launch_bounds__(256) void k_scan1(const float* __restrict__ xs,
                                               const float* __restrict__ dsp,
                                               const float* __restrict__ xdbl,
                                               const float* __restrict__ A_logs,
                                               float* __restrict__ prodA,
                                               float* __restrict__ hfin) {
    int t = blockIdx.x * 256 + threadIdx.x;
    if (t >= KD * NCH * NN) return;
    int n = t & 15;
    int gc = t >> 4;                                   // gid*NCH + c
    int c = gc & (NCH - 1);
    int gid = gc >> 7;                                 // /NCH
    int k = gid / DIN;
    float A = -__expf(A_logs[gid * NN + n]);
    const float4* dp4 = (const float4*)(dsp + gid * LL + c * CHL);
    const float4* up4 = (const float4*)(xs + gid * LL + c * CHL);
    const float* bp = xdbl + ((size_t)(k * LL + c * CHL)) * 35 + 3 + n;
    float h = 0.f, pa = 1.f;
#pragma unroll 2
    for (int i4 = 0; i4 < CHL / 4; ++i4) {
        float4 dv = dp4[i4];
        float4 uv = up4[i4];
#pragma unroll
        for (int j = 0; j < 4; ++j) {
            float delta = (&dv.x)[j];
            float u = (&uv.x)[j];
            float Bv = bp[(size_t)(i4 * 4 + j) * 35];
            float dA = __expf(delta * A);
            h = h * dA + delta * u * Bv;
            pa *= dA;
        }
    }
    prodA[t] = pa;
    hfin[t] = h;
}

// Phase 2: sequential combine across the NCH chunk summaries (tiny).
__global__ __launch_bounds__(256) void k_scan2(const float* __restrict__ prodA,
                                               const float* __restrict__ hfin,
                                               float* __restrict__ h0) {
    int t = blockIdx.x * 256 + threadIdx.x;            // gid*16 + n
    if (t >= KD * NN) return;
    int n = t & 15;
    int gid = t >> 4;
    size_t base = (size_t)gid * NCH * 16 + n;
    float h = 0.f;
#pragma unroll 4
    for (int c = 0; c < NCH; ++c) {
        size_t idx = base + (size_t)c * 16;
        h0[idx] = h;
        h = h * prodA[idx] + hfin[idx];
    }
}

// Phase 3: re-scan each chunk seeded with h0, emit y.
__global__ __launch_bounds__(256) void k_scan3(const float* __restrict__ xs,
                                               const float* __restrict__ dsp,
                                               const float* __restrict__ xdbl,
                                               const float* __restrict__ A_logs,
                                               const float* __restrict__ Ds,
                                               const float* __restrict__ h0,
                                               float* __restrict__ y) {
    int t = blockIdx.x * 256 + threadIdx.x;
    if (t >= KD * NCH * NN) return;
    int n = t & 15;
    int gc = t >> 4;
    int c = gc & (NCH - 1);
    int gid = gc >> 7;
    int k = gid / DIN;
    float A = -__expf(A_logs[gid * NN + n]);
    float Dv = Ds[gid];
    const float4* dp4 = (const float4*)(dsp + gid * LL + c * CHL);
    const float4* up4 = (const float4*)(xs + gid * LL + c * CHL);
    const float* bp = xdbl + ((size_t)(k * LL + c * CHL)) * 35 + 3 + n;
    const float* cp = xdbl + ((size_t)(k * LL + c * CHL)) * 35 + 19 + n;
    float4* yp4 = (float4*)(y + gid * LL + c * CHL);
    float h = h0[t];
#pragma unroll 2
    for (int i4 = 0; i4 < CHL / 4; ++i4) {
        float4 dv = dp4[i4];
        float4 uv = up4[i4];
        float4 yv;
#pragma unroll
        for (int j = 0; j < 4; ++j) {
            float delta = (&dv.x)[j];
            float u = (&uv.x)[j];
            size_t off = (size_t)(i4 * 4 + j) * 35;
            float Bv = bp[off];
            float Cv = cp[off];
            float dA = __expf(delta * A);
            h = h * dA + delta * u * Bv;
            float p = h * Cv;
            p += __shfl_xor(p, 1, 64);
            p += __shfl_xor(p, 2, 64);
            p += __shfl_xor(p, 4, 64);
            p += __shfl_xor(p, 8, 64);
            (&yv.x)[j] = p + Dv * u;
        }
        if (n == 0) yp4[i4] = yv;
    }
}

// ------------- Kernel 7: merge dirs + LayerNorm + gate + out_proj -----------
__global__ __launch_bounds__(64) void k_final(const float* __restrict__ y,
                                              const float* __restrict__ z,
                                              const float* __restrict__ nw,
                                              const float* __restrict__ nb,
                                              const float* __restrict__ opw,
                                              float* __restrict__ out) {
    int s = blockIdx.x;                                // spatial (h,w,dd)
    int lane = threadIdx.x;                            // 0..63
    int dd = s & 15, w = (s >> 4) & 15, h = s >> 8;
    int l0 = s;
    int l1 = w * 256 + h * 16 + dd;
    int l2 = dd * 256 + w * 16 + h;
    int l3 = h * 256 + dd * 16 + w;
    __shared__ float g[DIN];
    float val = 0.f;
    if (lane < DIN) {
        int d = lane;
        val = y[(0 * DIN + d) * LL + l0] + y[(4 * DIN + d) * LL + (LL - 1 - l0)]
            + y[(1 * DIN + d) * LL + l1] + y[(5 * DIN + d) * LL + (LL - 1 - l1)]
            + y[(2 * DIN + d) * LL + l2] + y[(6 * DIN + d) * LL + (LL - 1 - l2)]
            + y[(3 * DIN + d) * LL + l3] + y[(7 * DIN + d) * LL + (LL - 1 - l3)];
    }
    float m = val;
#pragma unroll
    for (int o = 32; o >= 1; o >>= 1) m += __shfl_xor(m, o, 64);
    m *= (1.f / 48.f);
    float dv = (lane < DIN) ? (val - m) : 0.f;
    float v2 = dv * dv;
#pragma unroll
    for (int o = 32; o >= 1; o >>= 1) v2 += __shfl_xor(v2, o, 64);
    v2 *= (1.f / 48.f);
    float inv = rsqrtf(v2 + 1e-5f);
    if (lane < DIN) {
        float yn = dv * inv * nw[lane] + nb[lane];
        float zz = z[s * DIN + lane];
        g[lane] = yn * (zz / (1.f + __expf(-zz)));     // * silu(z)
    }
    __syncthreads();
    if (lane < DIN) {
        const float* wr = opw + lane * DIN;            // out_proj_w[c, e], c=lane
        float acc = 0.f;
#pragma unroll
        for (int e = 0; e < DIN; ++e) acc += g[e] * wr[e];
        out[s * CC + lane] = acc;
    }
}

extern "C" void kernel_launch(void* const* d_in, const int* in_sizes, int n_in,
                              void* d_out, int out_size, void* d_ws, size_t ws_size,
                              hipStream_t stream) {
    const float* x      = (const float*)d_in[0];
    const float* ipw    = (const float*)d_in[1];
    const float* cw     = (const float*)d_in[2];
    const float* cb     = (const float*)d_in[3];
    const float* xpw    = (const float*)d_in[4];
    const float* dtw    = (const float*)d_in[5];
    const float* dtb    = (const float*)d_in[6];
    const float* A_logs = (const float*)d_in[7];
    const float* Ds     = (const float*)d_in[8];
    const float* nw     = (const float*)d_in[9];
    const float* nb     = (const float*)d_in[10];
    const float* opw    = (const float*)d_in[11];
    float* out = (float*)d_out;

    float* ws    = (float*)d_ws;
    float* xm    = ws;                          // DIN*LL
    float* z     = xm + DIN * LL;               // LL*DIN
    float* xc    = z + LL * DIN;                // DIN*LL
    float* xs    = xc + DIN * LL;               // KD*LL
    float* xdbl  = xs + (size_t)KD * LL;        // K*LL*35
    float* dsp   = xdbl + (size_t)KK * LL * 35; // KD*LL
    float* y     = dsp + (size_t)KD * LL;       // KD*LL
    float* prodA = y + (size_t)KD * LL;         // KD*NCH*16
    float* hfin  = prodA + (size_t)KD * NCH * 16;
    float* h0    = hfin + (size_t)KD * NCH * 16;

    k_inproj<<<(LL * 96 + 255) / 256, 256, 0, stream>>>(x, ipw, xm, z);
    k_conv<<<(DIN * LL + 255) / 256, 256, 0, stream>>>(xm, cw, cb, xc);
    k_scatter<<<(KD * (LL / 4) + 255) / 256, 256, 0, stream>>>(xc, xs);
    k_xproj<<<(KK * (LL / 4) * 35 + 255) / 256, 256, 0, stream>>>(xs, xpw, xdbl);
    k_delta<<<(KD * (LL / 4) + 255) / 256, 256, 0, stream>>>(xdbl, dtw, dtb, dsp);

    int scan_threads = KD * NCH * NN;                  // 786432
    k_scan1<<<(scan_threads + 255) / 256, 256, 0, stream>>>(xs, dsp, xdbl, A_logs, prodA, hfin);
    k_scan2<<<(KD * NN + 255) / 256, 256, 0, stream>>>(prodA, hfin, h0);
    k_scan3<<<(scan_threads + 255) / 256, 256, 0, stream>>>(xs, dsp, xdbl, A_logs, Ds, h0, y);

    k_final<<<LL, 64, 0, stream>>>(y, z, nw, nb, opw, out);
}

// Round 4
// 167.346 us; speedup vs baseline: 9.5531x; 1.0557x over previous
//
#include <hip/hip_runtime.h>
#include <hip/hip_bf16.h>
#include <math.h>

// Problem constants (B=1)
#define HH 16
#define WW 16
#define DD 16
#define LL 4096          // H*W*Dd
#define CC 48            // d_model
#define DIN 48           // d_inner
#define NN 16            // d_state
#define RR 3             // dt_rank
#define KK 8             // scan directions
#define KD 384           // K*DIN
#define SNCH 64          // chunks along L (fused scan)
#define SCHL 64          // chunk length

// ---------------- Kernel 1: in_proj  xz[l,e] = sum_c x[l,c]*W[e,c] ----------
// xm stored channels-first (DIN, L); z stored (L, DIN)
__global__ __launch_bounds__(256) void k_inproj(const float* __restrict__ x,
                                                const float* __restrict__ W,
                                                float* __restrict__ xm,
                                                float* __restrict__ z) {
    int tid = blockIdx.x * 256 + threadIdx.x;          // l*96 + e
    if (tid >= LL * 96) return;
    int e = tid % 96, l = tid / 96;
    const float4* xr = (const float4*)(x + l * CC);
    const float4* wr = (const float4*)(W + e * CC);
    float acc = 0.f;
#pragma unroll
    for (int c4 = 0; c4 < CC / 4; ++c4) {
        float4 a = xr[c4], b = wr[c4];
        acc += a.x * b.x + a.y * b.y + a.z * b.z + a.w * b.w;
    }
    if (e < DIN) xm[e * LL + l] = acc;
    else         z[l * DIN + (e - DIN)] = acc;
}

// ---- Kernel 2: depthwise 3x3x3 conv + bias + SiLU + 8-way scatter to xs ----
// Permutations are involutions: position s lands at scan-index perm(s) in
// dirs 0..3 and LL-1-perm(s) in dirs 4..7.
__global__ __launch_bounds__(256) void k_convscat(const float* __restrict__ xm,
                                                  const float* __restrict__ cw,
                                                  const float* __restrict__ cb,
                                                  float* __restrict__ xs) {
    int tid = blockIdx.x * 256 + threadIdx.x;          // d*LL + s
    if (tid >= DIN * LL) return;
    int s = tid & (LL - 1), d = tid >> 12;
    int dd = s & 15, w = (s >> 4) & 15, h = s >> 8;
    const float* wp = cw + d * 27;
    const float* xp = xm + d * LL;
    float acc = 0.f;
#pragma unroll
    for (int i = -1; i <= 1; ++i) {
        int hh = h + i; if (hh < 0 || hh > 15) continue;
#pragma unroll
        for (int j = -1; j <= 1; ++j) {
            int ww2 = w + j; if (ww2 < 0 || ww2 > 15) continue;
#pragma unroll
            for (int q = -1; q <= 1; ++q) {
                int dd2 = dd + q; if (dd2 < 0 || dd2 > 15) continue;
                acc += wp[(i + 1) * 9 + (j + 1) * 3 + (q + 1)]
                     * xp[hh * 256 + ww2 * 16 + dd2];
            }
        }
    }
    acc += cb[d];
    float v = acc / (1.f + __expf(-acc));              // SiLU
    int p0 = s;
    int p1 = w * 256 + h * 16 + dd;                    // swap h,w
    int p2 = dd * 256 + w * 16 + h;                    // swap h,dd
    int p3 = h * 256 + dd * 16 + w;                    // swap w,dd
    xs[(size_t)(0 * DIN + d) * LL + p0] = v;
    xs[(size_t)(1 * DIN + d) * LL + p1] = v;
    xs[(size_t)(2 * DIN + d) * LL + p2] = v;
    xs[(size_t)(3 * DIN + d) * LL + p3] = v;
    xs[(size_t)(4 * DIN + d) * LL + (LL - 1 - p0)] = v;
    xs[(size_t)(5 * DIN + d) * LL + (LL - 1 - p1)] = v;
    xs[(size_t)(6 * DIN + d) * LL + (LL - 1 - p2)] = v;
    xs[(size_t)(7 * DIN + d) * LL + (LL - 1 - p3)] = v;
}

// ---- Kernel 3: x_proj + dt_proj fused. Block per (k, 64-l tile). ----------
// Emits BC[k][l][32] (n<16: B, n>=16: C) and dsp (softplus delta), (K*DIN, L).
__global__ __launch_bounds__(256) void k_xproj2(const float* __restrict__ xs,
                                                const float* __restrict__ xpw,
                                                const float* __restrict__ dtw,
                                                const float* __restrict__ dtb,
                                                float* __restrict__ BC,
                                                float* __restrict__ dsp) {
    int k = blockIdx.x >> 6;
    int l0 = (blockIdx.x & 63) * 64;
    int tid = threadIdx.x;
    __shared__ float xd[35 * 65];                      // x_dbl tile, pad 65
    __shared__ float wl[35 * 49];                      // weights, pad 49
    for (int i = tid; i < 35 * 48; i += 256)
        wl[(i / 48) * 49 + (i % 48)] = xpw[k * 35 * 48 + i];
    __syncthreads();
    // Phase A: x_dbl[c][l] for c=0..34, l tile of 64 (as 16 float4 groups)
#pragma unroll
    for (int it = 0; it < 3; ++it) {
        int item = it * 256 + tid;
        if (item < 560) {
            int c = item % 35, l4 = item / 35;
            const float4* xr = (const float4*)(xs + (size_t)k * DIN * LL + l0) + l4;
            const float* wr = wl + c * 49;
            float4 acc = {0.f, 0.f, 0.f, 0.f};
#pragma unroll
            for (int d2 = 0; d2 < 48; ++d2) {
                float4 v = xr[(size_t)d2 * (LL / 4)];
                float w = wr[d2];
                acc.x += v.x * w; acc.y += v.y * w; acc.z += v.z * w; acc.w += v.w * w;
            }
            float* o = xd + c * 65 + l4 * 4;
            o[0] = acc.x; o[1] = acc.y; o[2] = acc.z; o[3] = acc.w;
        }
    }
    __syncthreads();
    // Phase B: write B/C rows (c=3..34) coalesced, stride-32 layout
#pragma unroll
    for (int it = 0; it < 8; ++it) {
        int idx = it * 256 + tid;                      // 2048 = 64 l * 32 c
        int l = idx >> 5, c = idx & 31;
        BC[((size_t)k * LL + l0 + l) * 32 + c] = xd[(c + 3) * 65 + l];
    }
    // Phase C: delta = softplus(dts @ dtw + bias)
#pragma unroll
    for (int it = 0; it < 12; ++it) {
        int idx = it * 256 + tid;                      // 3072 = 48 d * 64 l
        int d2 = idx >> 6, l = idx & 63;
        int gd = k * DIN + d2;
        float v = xd[l] * dtw[gd * 3] + xd[65 + l] * dtw[gd * 3 + 1]
                + xd[130 + l] * dtw[gd * 3 + 2] + dtb[gd];
        dsp[(size_t)gd * LL + l0 + l] = (v > 20.f) ? v : log1pf(__expf(v));
    }
}

// ---- Kernel 4: fused 3-phase selective scan. Block per gid=(k,d). ----------
// 1024 threads = 64 chunks x 16 states. u/delta staged in LDS (one global
// read). In-block chunk-summary combine. Stores y de-permuted: y2[s][k][d].
__global__ __launch_bounds__(1024) void k_scanf(const float* __restrict__ xs,
                                                const float* __restrict__ dsp,
                                                const float* __restrict__ BC,
                                                const float* __restrict__ A_logs,
                                                const float* __restrict__ Ds,
                                                float* __restrict__ y2) {
    int gid = blockIdx.x;                              // k*DIN + d
    int k = gid / DIN;
    int d = gid - k * DIN;
    int t = threadIdx.x;
    int n = t & 15, c = t >> 4;                        // c: 0..63
    __shared__ float u_lds[LL];
    __shared__ float d_lds[LL];
    __shared__ float pa_lds[SNCH * 16];
    __shared__ float hf_lds[SNCH * 16];
    __shared__ float h0_lds[SNCH * 16];
    {
        const float4* up4 = (const float4*)(xs + (size_t)gid * LL);
        const float4* dp4 = (const float4*)(dsp + (size_t)gid * LL);
        float4* ul = (float4*)u_lds;
        float4* dl = (float4*)d_lds;
        for (int i = t; i < LL / 4; i += 1024) { ul[i] = up4[i]; dl[i] = dp4[i]; }
    }
    __syncthreads();
    float A = -__expf(A_logs[gid * NN + n]);
    const float* bp = BC + ((size_t)k * LL + c * SCHL) * 32 + n;
    const float* cp = bp + 16;
    int base = c * SCHL;
    // Phase 1: local chunk scan
    float h = 0.f, pa = 1.f;
#pragma unroll 4
    for (int i = 0; i < SCHL; ++i) {
        float delta = d_lds[base + i];
        float u = u_lds[base + i];
        float Bv = bp[(size_t)i * 32];
        float dA = __expf(delta * A);
        h = h * dA + delta * u * Bv;
        pa *= dA;
    }
    pa_lds[t] = pa;
    hf_lds[t] = h;
    __syncthreads();
    // Phase 2: serial combine over 64 chunks (16 lanes, one per state)
    if (t < 16) {
        float hh = 0.f;
#pragma unroll 8
        for (int cc = 0; cc < SNCH; ++cc) {
            int idx = cc * 16 + t;
            h0_lds[idx] = hh;
            hh = hh * pa_lds[idx] + hf_lds[idx];
        }
    }
    __syncthreads();
    // Phase 3: re-scan seeded with h0, reduce over n, scatter-store de-permuted
    h = h0_lds[t];
    float Dv = Ds[gid];
#pragma unroll 4
    for (int i = 0; i < SCHL; ++i) {
        float delta = d_lds[base + i];
        float u = u_lds[base + i];
        float Bv = bp[(size_t)i * 32];
        float Cv = cp[(size_t)i * 32];
        float dA = __expf(delta * A);
        h = h * dA + delta * u * Bv;
        float p = h * Cv;
        p += __shfl_xor(p, 1, 64);
        p += __shfl_xor(p, 2, 64);
        p += __shfl_xor(p, 4, 64);
        p += __shfl_xor(p, 8, 64);
        if (n == 0) {
            int l = base + i;
            int ll = (k & 4) ? (LL - 1 - l) : l;
            int a = ll >> 8, b2 = (ll >> 4) & 15, c2 = ll & 15;
            int s;
            switch (k & 3) {
                case 0: s = ll;                        break;
                case 1: s = b2 * 256 + a * 16 + c2;    break;
                case 2: s = c2 * 256 + b2 * 16 + a;    break;
                default: s = a * 256 + c2 * 16 + b2;   break;
            }
            y2[((size_t)s * KK + k) * DIN + d] = p + Dv * u;
        }
    }
}

// ---- Kernel 5: sum dirs + LayerNorm + gate + out_proj. Wave per s. ---------
__global__ __launch_bounds__(256) void k_final2(const float* __restrict__ y2,
                                                const float* __restrict__ z,
                                                const float* __restrict__ nw,
                                                const float* __restrict__ nb,
                                                const float* __restrict__ opw,
                                                float* __restrict__ out) {
    int wv = threadIdx.x >> 6, lane = threadIdx.x & 63;
    int s = blockIdx.x * 4 + wv;
    __shared__ float g[4][DIN];
    float val = 0.f;
    if (lane < DIN) {
        const float* yp = y2 + (size_t)s * (KK * DIN) + lane;
#pragma unroll
        for (int k = 0; k < KK; ++k) val += yp[k * DIN];
    }
    float m = val;
#pragma unroll
    for (int o = 32; o >= 1; o >>= 1) m += __shfl_xor(m, o, 64);
    m *= (1.f / 48.f);
    float dv = (lane < DIN) ? (val - m) : 0.f;
    float v2 = dv * dv;
#pragma unroll
    for (int o = 32; o >= 1; o >>= 1) v2 += __shfl_xor(v2, o, 64);
    v2 *= (1.f / 48.f);
    float inv = rsqrtf(v2 + 1e-5f);
    if (lane < DIN) {
        float yn = dv * inv * nw[lane] + nb[lane];
        float zz = z[s * DIN + lane];
        g[wv][lane] = yn * (zz / (1.f + __expf(-zz)));
    }
    __syncthreads();
    if (lane < DIN) {
        const float* wr = opw + lane * DIN;            // out_proj_w[c, e]
        float acc = 0.f;
#pragma unroll
        for (int e = 0; e < DIN; ++e) acc += g[wv][e] * wr[e];
        out[s * CC + lane] = acc;
    }
}

extern "C" void kernel_launch(void* const* d_in, const int* in_sizes, int n_in,
                              void* d_out, int out_size, void* d_ws, size_t ws_size,
                              hipStream_t stream) {
    const float* x      = (const float*)d_in[0];
    const float* ipw    = (const float*)d_in[1];
    const float* cw     = (const float*)d_in[2];
    const float* cb     = (const float*)d_in[3];
    const float* xpw    = (const float*)d_in[4];
    const float* dtw    = (const float*)d_in[5];
    const float* dtb    = (const float*)d_in[6];
    const float* A_logs = (const float*)d_in[7];
    const float* Ds     = (const float*)d_in[8];
    const float* nw     = (const float*)d_in[9];
    const float* nb     = (const float*)d_in[10];
    const float* opw    = (const float*)d_in[11];
    float* out = (float*)d_out;

    float* ws  = (float*)d_ws;
    float* xm  = ws;                                   // DIN*LL
    float* z   = xm + DIN * LL;                        // LL*DIN
    float* xs  = z + LL * DIN;                         // KD*LL
    float* BC  = xs + (size_t)KD * LL;                 // KK*LL*32
    float* dsp = BC + (size_t)KK * LL * 32;            // KD*LL
    float* y2  = dsp + (size_t)KD * LL;                // LL*KK*DIN

    k_inproj<<<(LL * 96 + 255) / 256, 256, 0, stream>>>(x, ipw, xm, z);
    k_convscat<<<(DIN * LL + 255) / 256, 256, 0, stream>>>(xm, cw, cb, xs);
    k_xproj2<<<KK * 64, 256, 0, stream>>>(xs, xpw, dtw, dtb, BC, dsp);
    k_scanf<<<KD, 1024, 0, stream>>>(xs, dsp, BC, A_logs, Ds, y2);
    k_final2<<<LL / 4, 256, 0, stream>>>(y2, z, nw, nb, opw, out);
}